// Round 6
// baseline (1813.075 us; speedup 1.0000x reference)
//
#include <hip/hip_runtime.h>

// Slater-determinant ordered sampler, D=512 sites, N=128 particles.
//
// Blocked N x N inverse-block recursion (algebra verified, passed r2-r5):
//   per block of B=32 sites: S = Pb A Pb^T; single-wave register scan on S
//   (decision logic identical to reference); A += (V U) D^-1 (V U)^T with
//   V = A Pb^T, U = unit-upper built in the scan (fused, readlane-based).
//
// Round-6: the r5 bottleneck was latency (VALUBusy ~14% on-CU, 2 waves/SIMD
// can't hide ~120cyc LDS latency). Changes:
//  * 1024 threads = 16 waves = 4 waves/SIMD (max for this LDS footprint).
//    Wave w owns A cols [8w,8w+8); lane owns rows {lane, lane+64}.
//  * atomicAdd (ds_add_f32) for the V cross-wave reduction, not
//    unsafeAtomicAdd (generic-ptr path can lower to flat CAS).
//  * 5 barriers/block: VT re-zero folded into A-update; P staging for
//    block b+1 runs during the scan (waves 1-8).
//  * All phases sized for the 128-VGPR cap of launch_bounds(1024,4).
// LDS ~63.2 KB.

#define DD 512
#define NN 128
#define BB 32
#define NTH 1024
#define TINYF 1e-30f

__device__ __forceinline__ float rdlane(float v, int l) {
  return __uint_as_float(__builtin_amdgcn_readlane(__float_as_uint(v), l));
}

__global__ __launch_bounds__(NTH, 4)
void slater_blk6(const float* __restrict__ P, const float* __restrict__ u,
                 float* __restrict__ out) {
  const int tid  = threadIdx.x;
  const int wave = tid >> 6;
  const int lane = tid & 63;
  const int c0   = wave << 3;  // 8 A-columns per wave

  __shared__ __align__(16) float buf[2][128][36];  // PbT (dbl-buf) / Wmat
  __shared__ __align__(16) float VT[32][132];      // VT[t][r] = V[r][t]
  __shared__ __align__(16) float Smat[32][33];
  __shared__ __align__(16) float Umat[32][36];
  __shared__ __align__(16) float invpSh[32];
  __shared__ float ush[NN];
  __shared__ int kSh;

  // Zero cond_probs (harness poisons d_out); positions all get written.
  {
    const float4 z = make_float4(0.f, 0.f, 0.f, 0.f);
    float4* o4 = (float4*)out;
#pragma unroll
    for (int j = 0; j < 16; ++j) o4[tid + j * NTH] = z;
  }
  if (tid < NN) ush[tid] = u[tid];

  // Stage block 0 into buf[0]: PbT[c][t] = P[t][c].
  if (tid < 512) {
    const int t = tid & 31, cb = (tid >> 5) << 3;
    const float* src = P + t * NN + cb;
    const float4 a = *(const float4*)src;
    const float4 b = *(const float4*)(src + 4);
    buf[0][cb + 0][t] = a.x; buf[0][cb + 1][t] = a.y;
    buf[0][cb + 2][t] = a.z; buf[0][cb + 3][t] = a.w;
    buf[0][cb + 4][t] = b.x; buf[0][cb + 5][t] = b.y;
    buf[0][cb + 6][t] = b.z; buf[0][cb + 7][t] = b.w;
  }
  // Zero VT (accumulated by ds_add_f32 atomics).
  {
    const float4 z = make_float4(0.f, 0.f, 0.f, 0.f);
    float4* v4 = (float4*)VT;
    for (int j = tid; j < (32 * 132) / 4; j += NTH) v4[j] = z;
  }

  // A = I_N distributed: A0[j]=A[lane][c0+j], A1[j]=A[lane+64][c0+j].
  float A0[8], A1[8];
#pragma unroll
  for (int j = 0; j < 8; ++j) {
    A0[j] = (lane == c0 + j) ? 1.0f : 0.0f;
    A1[j] = (lane + 64 == c0 + j) ? 1.0f : 0.0f;
  }

  // Scan state (only wave 0's copy is live across blocks).
  float ratio = 1.0f, cumul = 0.0f, uk_cur = u[0];
  int k = 0;

  __syncthreads();  // B0 (init)

#pragma unroll 1
  for (int blk = 0; blk < DD / BB; ++blk) {
    const int i0 = blk * BB;
    float (*pb)[36] = buf[blk & 1];

    // ---- V = A Pb^T: 2 half-passes, ds_add_f32 reduce into VT ----
#pragma unroll 1
    for (int half = 0; half < 2; ++half) {
      const int tb = half << 4;
      float vp0[16], vp1[16];
#pragma unroll
      for (int t = 0; t < 16; ++t) { vp0[t] = 0.f; vp1[t] = 0.f; }
#pragma unroll
      for (int j = 0; j < 8; ++j) {
        const float a0 = A0[j], a1 = A1[j];
        const float* row = &pb[c0 + j][tb];  // wave-uniform -> broadcast
#pragma unroll
        for (int t4 = 0; t4 < 4; ++t4) {
          const float4 pv = *(const float4*)&row[t4 * 4];
          vp0[4 * t4 + 0] = fmaf(a0, pv.x, vp0[4 * t4 + 0]);
          vp0[4 * t4 + 1] = fmaf(a0, pv.y, vp0[4 * t4 + 1]);
          vp0[4 * t4 + 2] = fmaf(a0, pv.z, vp0[4 * t4 + 2]);
          vp0[4 * t4 + 3] = fmaf(a0, pv.w, vp0[4 * t4 + 3]);
          vp1[4 * t4 + 0] = fmaf(a1, pv.x, vp1[4 * t4 + 0]);
          vp1[4 * t4 + 1] = fmaf(a1, pv.y, vp1[4 * t4 + 1]);
          vp1[4 * t4 + 2] = fmaf(a1, pv.z, vp1[4 * t4 + 2]);
          vp1[4 * t4 + 3] = fmaf(a1, pv.w, vp1[4 * t4 + 3]);
        }
      }
#pragma unroll
      for (int t = 0; t < 16; ++t) {
        atomicAdd(&VT[tb + t][lane], vp0[t]);        // ds_add_f32
        atomicAdd(&VT[tb + t][lane + 64], vp1[t]);
      }
    }
    __syncthreads();  // B1

    // ---- S = Pb V: one (d,t) entry per thread; Pb rows from L1 ----
    {
      const int t = tid & 31;
      const int d = (tid >> 5) & 31;
      const float* prow = P + (i0 + d) * NN;
      float s0 = 0.f;
#pragma unroll
      for (int r4 = 0; r4 < 32; ++r4) {
        const float4 v4 = *(const float4*)&VT[t][r4 * 4];
        const float4 pa = *(const float4*)&prow[r4 * 4];
        s0 = fmaf(pa.x, v4.x, s0); s0 = fmaf(pa.y, v4.y, s0);
        s0 = fmaf(pa.z, v4.z, s0); s0 = fmaf(pa.w, v4.w, s0);
      }
      Smat[d][t] = s0;
    }
    __syncthreads();  // B2

    // ---- wave 0: scan.  waves 1-8: stage next block's PbT ----
    if (wave == 0) {
      const int a = lane & 31;
      float Sreg[32], Ucols[32];
#pragma unroll
      for (int j = 0; j < 32; ++j) {
        Sreg[j] = Smat[a][j];
        Ucols[j] = 0.f;
      }
#pragma unroll 32
      for (int t = 0; t < BB; ++t) {
        const int i = i0 + t;
        const float x = Sreg[t];
        const float stt = rdlane(x, t);
        const float s = 1.0f - stt;
        const int la = DD - NN + k;
        const bool active = (k < NN) && (i <= la);
        const float pr = active ? stt * ratio : 0.0f;
        const bool occupy = active && ((cumul + pr >= uk_cur) || (i == la));
        float pivot = occupy ? (s - 1.0f) : s;
        pivot = (fabsf(pivot) < TINYF) ? TINYF : pivot;
        const float invp = 1.0f / pivot;
        if (lane == 0) {
          if (k < NN) out[k * DD + i] = pr;
          if (occupy) out[NN * DD + k] = (float)i;
          invpSh[t] = invp;
        }
        ratio = occupy ? 1.0f : (active ? ratio * s : ratio);
        cumul = occupy ? 0.0f : (cumul + pr);
        k += occupy ? 1 : 0;
        uk_cur = ush[(k < NN) ? k : (NN - 1)];  // prefetch next threshold
        Ucols[t] += (a == t) ? 1.0f : 0.0f;     // identity before use
        const float y = x * invp;
        const float g = Ucols[t] * invp;
#pragma unroll
        for (int b = t + 1; b < BB; ++b) {
          const float xb = rdlane(x, b);        // SGPR broadcast
          Sreg[b] = fmaf(y, xb, Sreg[b]);       // S~ rank-1 (r2-r5 values)
          Ucols[b] = fmaf(g, xb, Ucols[b]);     // fused U-build
        }
      }
      if (lane < 32) {
#pragma unroll
        for (int j8 = 0; j8 < 8; ++j8)
          *(float4*)&Umat[lane][4 * j8] =
              make_float4(Ucols[4 * j8], Ucols[4 * j8 + 1],
                          Ucols[4 * j8 + 2], Ucols[4 * j8 + 3]);
      }
      if (lane == 0) kSh = k;
    } else if (wave <= 8 && blk + 1 < DD / BB) {
      // Stage PbT for block blk+1 into the other buffer (off critical path).
      const int q = tid - 64;                    // 0..511
      const int t = q & 31, cb = (q >> 5) << 3;  // 16 groups x 8 cols
      const float* src = P + (i0 + BB + t) * NN + cb;
      const float4 a = *(const float4*)src;
      const float4 b = *(const float4*)(src + 4);
      float (*nb)[36] = buf[(blk & 1) ^ 1];
      nb[cb + 0][t] = a.x; nb[cb + 1][t] = a.y;
      nb[cb + 2][t] = a.z; nb[cb + 3][t] = a.w;
      nb[cb + 4][t] = b.x; nb[cb + 5][t] = b.y;
      nb[cb + 6][t] = b.z; nb[cb + 7][t] = b.w;
    }
    __syncthreads();  // B3

    if (blk == DD / BB - 1 || kSh >= NN) break;  // uniform; outputs complete

    // ---- W = V U (into pb over dead PbT); full 32-j unroll ----
    {
      const int r = tid & 127;
      const int t0 = (tid >> 7) << 2;  // 4 t-columns per thread
      float wacc[4];
#pragma unroll
      for (int tt = 0; tt < 4; ++tt) wacc[tt] = 0.f;
#pragma unroll
      for (int j = 0; j < 32; ++j) {
        const float vv = VT[j][r];
        const float4 ua = *(const float4*)&Umat[j][t0];
        wacc[0] = fmaf(vv, ua.x, wacc[0]);
        wacc[1] = fmaf(vv, ua.y, wacc[1]);
        wacc[2] = fmaf(vv, ua.z, wacc[2]);
        wacc[3] = fmaf(vv, ua.w, wacc[3]);
      }
      *(float4*)&pb[r][t0] = make_float4(wacc[0], wacc[1], wacc[2], wacc[3]);
    }
    __syncthreads();  // B4

    // ---- zero VT for next block (VT dead after W), then A += Wd W^T ----
    {
      const float4 z = make_float4(0.f, 0.f, 0.f, 0.f);
      float4* v4 = (float4*)VT;
      for (int j = tid; j < (32 * 132) / 4; j += NTH) v4[j] = z;
    }
    {
      float wd0[32], wd1[32];
#pragma unroll
      for (int t8 = 0; t8 < 8; ++t8) {
        const float4 ivq = *(const float4*)&invpSh[4 * t8];
        const float4 wa = *(const float4*)&pb[lane][4 * t8];
        const float4 wb = *(const float4*)&pb[lane + 64][4 * t8];
        wd0[4 * t8 + 0] = wa.x * ivq.x;
        wd0[4 * t8 + 1] = wa.y * ivq.y;
        wd0[4 * t8 + 2] = wa.z * ivq.z;
        wd0[4 * t8 + 3] = wa.w * ivq.w;
        wd1[4 * t8 + 0] = wb.x * ivq.x;
        wd1[4 * t8 + 1] = wb.y * ivq.y;
        wd1[4 * t8 + 2] = wb.z * ivq.z;
        wd1[4 * t8 + 3] = wb.w * ivq.w;
      }
#pragma unroll
      for (int j = 0; j < 8; ++j) {
        const float* wrow = &pb[c0 + j][0];  // wave-uniform broadcast
        float a0 = A0[j], a1 = A1[j];
#pragma unroll
        for (int t4 = 0; t4 < 8; ++t4) {
          const float4 w4 = *(const float4*)&wrow[t4 * 4];
          a0 = fmaf(wd0[4 * t4 + 0], w4.x, a0);
          a0 = fmaf(wd0[4 * t4 + 1], w4.y, a0);
          a0 = fmaf(wd0[4 * t4 + 2], w4.z, a0);
          a0 = fmaf(wd0[4 * t4 + 3], w4.w, a0);
          a1 = fmaf(wd1[4 * t4 + 0], w4.x, a1);
          a1 = fmaf(wd1[4 * t4 + 1], w4.y, a1);
          a1 = fmaf(wd1[4 * t4 + 2], w4.z, a1);
          a1 = fmaf(wd1[4 * t4 + 3], w4.w, a1);
        }
        A0[j] = a0;
        A1[j] = a1;
      }
    }
    __syncthreads();  // B5: VT zeroed + Wmat consumed
  }
}

extern "C" void kernel_launch(void* const* d_in, const int* in_sizes, int n_in,
                              void* d_out, int out_size, void* d_ws,
                              size_t ws_size, hipStream_t stream) {
  const float* P = (const float*)d_in[0];  // (512, 128) row-major fp32
  const float* u = (const float*)d_in[1];  // (128,) fp32
  float* out = (float*)d_out;              // 65536 cond_probs + 128 positions
  hipLaunchKernelGGL(slater_blk6, dim3(1), dim3(NTH), 0, stream, P, u, out);
}